// Round 9
// baseline (273.156 us; speedup 1.0000x reference)
//
#include <hip/hip_runtime.h>
#include <math.h>

typedef _Float16 f16;
typedef __attribute__((ext_vector_type(8)))  _Float16 f16v8;
typedef __attribute__((ext_vector_type(4)))  __fp16   h16v4;
typedef __attribute__((ext_vector_type(16))) float    f32x16;
typedef __attribute__((ext_vector_type(4)))  float    f32x4;

namespace {
constexpr int kB = 64, kCin = 512, kT = 1024, kCout = 256;
constexpr size_t kWfragBytes = (size_t)32 * 8 * 2 * 64 * 16;   // 512 KiB [kc][osub][plane][lane][16B]
constexpr size_t kSBytes     = kCout * 4;
constexpr size_t kWsNeed     = kWfragBytes + kSBytes;          // no y buffer anymore
}

// ---- prep: W' = 32*W split into 2 f16 planes (low plane scaled 2^11), A-frag order ----
// A-frag (32x32x16): m(o) = lane&31, k = (lane>>5)*8 + j.  Block (0,0,0) also fills sarr.
__global__ void wsplit16_kernel(const float* __restrict__ W, const float* __restrict__ gamma,
                                const float* __restrict__ rvar,
                                f16* __restrict__ wfrag, float* __restrict__ sarr) {
    const int kc = blockIdx.x, osub = blockIdx.y, p = blockIdx.z;
    const int lane = threadIdx.x;
    const int o  = osub * 32 + (lane & 31);
    const int kb = kc * 16 + (lane >> 5) * 8;
    f16v8 frag;
#pragma unroll
    for (int j = 0; j < 8; ++j) {
        const float w = 32.0f * W[o * kCin + kb + j];   // 2^5 pre-scale (denorm guard)
        const f16 h = (f16)w;                           // RNE
        const float r = w - (float)h;                   // exact
        const f16 l = (f16)(r * 2048.0f);               // low plane scaled 2^11
        frag[j] = p ? l : h;
    }
    *reinterpret_cast<f16v8*>(wfrag + ((size_t)((kc * 8 + osub) * 2 + p) * 64 + lane) * 8) = frag;
    if (kc == 0 && osub == 0 && p == 0) {
#pragma unroll
        for (int j = 0; j < 4; ++j) {
            const int oo = j * 64 + lane;
            sarr[oo] = (float)((double)gamma[oo] / sqrt((double)rvar[oo] + 1e-5));
        }
    }
}

// ---- FUSED GEMM+BN+LIF: y never touches HBM ----
// R1-R8 lesson: the gemm sits at an ~86-97us wall regardless of structure, while
// total-gemm = ~160us every round (lif reading the 64MB y + y write + 65MB ws
// re-poison + launches). This kernel deletes the y buffer: block owns 64o x all t,
// loops over 8 t-chunks of 128; per chunk runs R8's VERIFIED K-loop engine
// verbatim (same staging/swizzle/cadence -> bit-identical y values), writes the
// 64x128 chunk to padded LDS, and wave 0 (64 lanes, one per o) runs the exact
// lif recurrence in t-order, carrying v/cnt in registers across chunks.
// Grid 256 = 1 block/CU; XCD decode puts the 4 o-quarter blocks of each b on the
// SAME XCD (bid&7) so x[b] (2MB) is read ~once from HBM and shared in its 4MB L2
// (R7 proved this pairing mechanism works: FETCH 135->68MB).
__global__ __launch_bounds__(512, 2)
void gemmlif_kernel(const float* __restrict__ x, const f16* __restrict__ wfrag,
                    const float* __restrict__ sarr, const float* __restrict__ rmean,
                    const float* __restrict__ beta, float* __restrict__ out) {
    __shared__ unsigned int Bd[4][128 * 20];   // staging, 40 KiB (R8 layout)
    __shared__ float ytile[64][132];           // y chunk [o][t], +4 pad, 33.8 KiB

    const int tid  = threadIdx.x;
    const int lane = tid & 63;
    const int wave = tid >> 6;
    const int n = lane & 31, q = lane >> 5;

    // XCD decode: 4 o-quarters of each b on the same XCD, dispatched close together
    const int bid     = blockIdx.x;
    const int r       = bid >> 3;
    const int quarter = r & 3;
    const int b       = (bid & 7) + 8 * (r >> 2);
    const int osub_loc = wave & 1;              // 0..1 within block (64 o)
    const int tsub     = wave >> 1;             // 0..3: which 32-t slice
    const int osg      = quarter * 2 + osub_loc; // global osub 0..7
    const float* __restrict__ xb = x + ((size_t)b << 19);   // b*512*1024
    const f16v8* __restrict__ wf = reinterpret_cast<const f16v8*>(wfrag);

    // staging role (identical to R8): st_t 0..127, kpp 0..3
    const int st_t = tid & 127;
    const int kpp  = tid >> 7;
    const int st_sw = (st_t >> 3) & 3;
    const int wr_base = 20 * st_t + 2 * (kpp & 1);
    const int s0 = ((0 + (kpp >> 1)) ^ st_sw) * 4;
    const int s1 = ((2 + (kpp >> 1)) ^ st_sw) * 4;

    // BN constants hoisted (per-wave o range fixed)
    f32x4 sv[4], mv[4], bv[4];
#pragma unroll
    for (int g = 0; g < 4; ++g) {
        const int og = osg * 32 + g * 8 + q * 4;
        sv[g] = *reinterpret_cast<const f32x4*>(sarr + og);
        mv[g] = *reinterpret_cast<const f32x4*>(rmean + og);
        bv[g] = *reinterpret_cast<const f32x4*>(beta + og);
    }

    // LIF state (wave 0: lane = o_loc)
    float vv = 0.0f;
    int   cnt = 0;

    f16v8 af[2][2];     // [buf][plane]
    float xq[4][4];     // [slot][row] 4-deep x prefetch queue

    auto loadA = [&](int kc, f16v8 (&ad)[2]) {
#pragma unroll
        for (int pp = 0; pp < 2; ++pp)
            ad[pp] = wf[(size_t)((kc * 8 + osg) * 2 + pp) * 64 + lane];
    };
    auto stage = [&](int buf, const float (&xd)[4]) {
        auto h01 = __builtin_amdgcn_cvt_pkrtz(xd[0], xd[1]);   // RTZ pack
        auto h23 = __builtin_amdgcn_cvt_pkrtz(xd[2], xd[3]);
        auto l01 = __builtin_amdgcn_cvt_pkrtz((xd[0] - (float)h01[0]) * 2048.0f,
                                              (xd[1] - (float)h01[1]) * 2048.0f);
        auto l23 = __builtin_amdgcn_cvt_pkrtz((xd[2] - (float)h23[0]) * 2048.0f,
                                              (xd[3] - (float)h23[1]) * 2048.0f);
        h16v4 hv, lv;
        hv[0] = h01[0]; hv[1] = h01[1]; hv[2] = h23[0]; hv[3] = h23[1];
        lv[0] = l01[0]; lv[1] = l01[1]; lv[2] = l23[0]; lv[3] = l23[1];
        *reinterpret_cast<h16v4*>(&Bd[buf][wr_base + s0]) = hv;   // ds_write_b64
        *reinterpret_cast<h16v4*>(&Bd[buf][wr_base + s1]) = lv;
    };

    for (int tc = 0; tc < 8; ++tc) {
        const int tg0 = tc * 128;
        f32x16 accA = {};   // hh
        f32x16 accB = {};   // cross (scaled 2^11)

        auto loadX = [&](int kc, float (&xd)[4]) {
            const float* px = xb + (size_t)(kc * 16 + 4 * kpp) * kT + tg0 + st_t;
#pragma unroll
            for (int rr = 0; rr < 4; ++rr) xd[rr] = px[(size_t)rr * kT];
        };
        auto domfma = [&](int buf, const f16v8 (&ad)[2]) {
            __builtin_amdgcn_s_setprio(1);
            const int t = tsub * 32 + n;
            const int sw = (t >> 3) & 3;
            const f16v8 bh = *reinterpret_cast<const f16v8*>(&Bd[buf][20 * t + 4 * ((0 + q) ^ sw)]);
            const f16v8 bl = *reinterpret_cast<const f16v8*>(&Bd[buf][20 * t + 4 * ((2 + q) ^ sw)]);
            accA = __builtin_amdgcn_mfma_f32_32x32x16_f16(ad[0], bh, accA, 0, 0, 0);
            accB = __builtin_amdgcn_mfma_f32_32x32x16_f16(ad[0], bl, accB, 0, 0, 0);
            accB = __builtin_amdgcn_mfma_f32_32x32x16_f16(ad[1], bh, accB, 0, 0, 0);
            __builtin_amdgcn_s_setprio(0);
        };

        // prologue (R8 cadence): fill 4-deep x queue, A buf 0, stage chunks 0 and 1
        loadX(0, xq[0]); loadX(1, xq[1]); loadX(2, xq[2]); loadX(3, xq[3]);
        loadA(0, af[0]);
        stage(0, xq[0]);
        stage(1, xq[1]);
        asm volatile("s_waitcnt lgkmcnt(0)\n\ts_barrier" ::: "memory");

        for (int kc4 = 0; kc4 < 8; ++kc4) {
#pragma unroll
            for (int u = 0; u < 4; ++u) {
                const int kc = kc4 * 4 + u;
                if (kc < 31) loadA(kc + 1, af[(u + 1) & 1]);
                if (kc < 30) stage((u + 2) & 3, xq[(u + 2) & 3]);   // stage chunk kc+2
                if (kc < 28) loadX(kc + 4, xq[u]);                  // refill slot
                domfma(u, af[u & 1]);
                if (u & 1)  // one barrier per 2 chunks; global loads stay in flight
                    asm volatile("s_waitcnt lgkmcnt(0)\n\ts_barrier" ::: "memory");
            }
        }

        // ---- epilogue: combine planes, BN affine, write y-chunk to LDS ----
        // C/D: col(t)=lane&31, row(o within 32)=(reg&3)+8*(reg>>2)+4*(lane>>5)
        {
            const f32x16 v = accA + accB * 4.8828125e-4f;   // + cross/2^11
            const int t_loc = tsub * 32 + n;
#pragma unroll
            for (int g = 0; g < 4; ++g)
#pragma unroll
                for (int r2 = 0; r2 < 4; ++r2) {
                    const int o_loc = osub_loc * 32 + g * 8 + q * 4 + r2;
                    // exact /32 un-scale, then BN (identical per-element op order)
                    const float val = (v[4 * g + r2] * 0.03125f - mv[g][r2]) * sv[g][r2] + bv[g][r2];
                    ytile[o_loc][t_loc] = val;
                }
        }
        asm volatile("s_waitcnt lgkmcnt(0)\n\ts_barrier" ::: "memory");   // ytile visible

        // ---- LIF over this t-chunk: wave 0, lane = o_loc, t ascending ----
        if (tid < 64) {
            const float* yrow = &ytile[tid][0];
            f32x4 pA[4], pB[4];
#pragma unroll
            for (int j = 0; j < 4; ++j) pA[j] = *reinterpret_cast<const f32x4*>(yrow + j * 4);
#pragma unroll
            for (int g = 0; g < 8; ++g) {
                f32x4* curp = (g & 1) ? pB : pA;
                f32x4* nxtp = (g & 1) ? pA : pB;
                if (g < 7) {
#pragma unroll
                    for (int j = 0; j < 4; ++j)
                        nxtp[j] = *reinterpret_cast<const f32x4*>(yrow + (g + 1) * 16 + j * 4);
                }
#pragma unroll
                for (int j = 0; j < 4; ++j)
#pragma unroll
                    for (int e = 0; e < 4; ++e) {
                        const float yv = curp[j][e];
                        vv = vv + (yv - vv) * 0.5f;          // bit-exact reference recurrence
                        if (vv - 1.0f >= 0.0f) { ++cnt; vv = 0.0f; }
                    }
            }
        }
        // no extra barrier: next prologue's barrier syncs (LIF lanes arrive late);
        // ytile is rewritten only after a full K-loop of barriers.
    }

    if (tid < 64)
        out[((size_t)b << 8) + (quarter << 6) + tid] = (float)cnt * (1.0f / 1024.0f);
}

// ---- fallback (round-1 fp32 fused path, unchanged) ----
namespace fb {
constexpr int kOTile = 32, kTTile = 128, kCc = 64;
constexpr int kNtt = kT / kTTile, kNcc = kCin / kCc, kYPad = 132;
}

__global__ void wt_transpose_kernel(const float* __restrict__ W, float* __restrict__ Wt) {
    int idx = blockIdx.x * 256 + threadIdx.x;
    int c = idx >> 8, o = idx & 255;
    Wt[idx] = W[o * kCin + c];
}

__global__ __launch_bounds__(256, 2)
void snn_fused_kernel(const float* __restrict__ x, const float* __restrict__ Wt,
                      const float* __restrict__ gamma, const float* __restrict__ beta,
                      const float* __restrict__ rmean, const float* __restrict__ rvar,
                      float* __restrict__ out) {
    using namespace fb;
    __shared__ float xs[kCc][kTTile];
    __shared__ float ws[kCc][kOTile];
    __shared__ float ytile[kOTile][kYPad];
    __shared__ float sarr[kOTile], barr[kOTile], marr[kOTile], vstate[kOTile];
    __shared__ int scnt[kOTile];
    const int tid = threadIdx.x, tx = tid & 31, ty = tid >> 5;
    const int b = blockIdx.y, o_blk = blockIdx.x * kOTile;
    if (tid < kOTile) {
        const int o = o_blk + tid;
        const double dinv = 1.0 / sqrt((double)rvar[o] + 1e-5);
        sarr[tid] = (float)(dinv * (double)gamma[o]);
        barr[tid] = beta[o]; marr[tid] = rmean[o];
        vstate[tid] = 0.0f; scnt[tid] = 0;
    }
    __syncthreads();
    const float* xb = x + (size_t)b * kCin * kT;
    for (int tt = 0; tt < kNtt; ++tt) {
        float acc[4][4];
#pragma unroll
        for (int i = 0; i < 4; ++i)
#pragma unroll
            for (int j = 0; j < 4; ++j) acc[i][j] = 0.0f;
        const int t0 = tt * kTTile;
        for (int cc = 0; cc < kNcc; ++cc) {
#pragma unroll
            for (int k = 0; k < 8; ++k) {
                const int f = tid + 256 * k;
                const int c = f >> 5, tq = f & 31;
                *reinterpret_cast<float4*>(&xs[c][tq * 4]) = *reinterpret_cast<const float4*>(
                    xb + (size_t)(cc * kCc + c) * kT + t0 + tq * 4);
            }
#pragma unroll
            for (int k = 0; k < 2; ++k) {
                const int f = tid + 256 * k;
                const int c = f >> 3, oq = f & 7;
                *reinterpret_cast<float4*>(&ws[c][oq * 4]) = *reinterpret_cast<const float4*>(
                    Wt + (size_t)(cc * kCc + c) * kCout + o_blk + oq * 4);
            }
            __syncthreads();
#pragma unroll 8
            for (int c = 0; c < kCc; ++c) {
                const float4 xv = *reinterpret_cast<const float4*>(&xs[c][tx * 4]);
                const float4 wv = *reinterpret_cast<const float4*>(&ws[c][ty * 4]);
                const float xf[4] = {xv.x, xv.y, xv.z, xv.w};
                const float wf4[4] = {wv.x, wv.y, wv.z, wv.w};
#pragma unroll
                for (int i = 0; i < 4; ++i)
#pragma unroll
                    for (int j = 0; j < 4; ++j) acc[i][j] += wf4[i] * xf[j];
            }
            __syncthreads();
        }
#pragma unroll
        for (int i = 0; i < 4; ++i) {
            const int o = ty * 4 + i;
            const float s = sarr[o], bb2 = barr[o], m = marr[o];
#pragma unroll
            for (int j = 0; j < 4; ++j) ytile[o][tx * 4 + j] = (acc[i][j] - m) * s + bb2;
        }
        __syncthreads();
        if (tid < kOTile) {
            float vvv = vstate[tid];
            int cnt2 = 0;
#pragma unroll 4
            for (int t = 0; t < kTTile; ++t) {
                const float yv = ytile[tid][t];
                vvv = vvv + (yv - vvv) * 0.5f;
                if (vvv - 1.0f >= 0.0f) { cnt2++; vvv = 0.0f; }
            }
            vstate[tid] = vvv; scnt[tid] += cnt2;
        }
        __syncthreads();
    }
    if (tid < kOTile) out[b * kCout + o_blk + tid] = (float)scnt[tid] * (1.0f / 1024.0f);
}

extern "C" void kernel_launch(void* const* d_in, const int* in_sizes, int n_in,
                              void* d_out, int out_size, void* d_ws, size_t ws_size,
                              hipStream_t stream) {
    const float* x     = (const float*)d_in[0];
    const float* W     = (const float*)d_in[1];
    const float* gamma = (const float*)d_in[2];
    const float* beta  = (const float*)d_in[3];
    const float* rmean = (const float*)d_in[4];
    const float* rvar  = (const float*)d_in[5];
    float* out = (float*)d_out;

    if (ws_size >= kWsNeed) {
        f16*   wfrag = (f16*)d_ws;
        float* sarr  = (float*)((char*)d_ws + kWfragBytes);
        wsplit16_kernel<<<dim3(32, 8, 2), 64, 0, stream>>>(W, gamma, rvar, wfrag, sarr);
        gemmlif_kernel<<<dim3(256), 512, 0, stream>>>(x, wfrag, sarr, rmean, beta, out);
    } else {
        float* Wt = (float*)d_ws;
        wt_transpose_kernel<<<(kCin * kCout) / 256, 256, 0, stream>>>(W, Wt);
        snn_fused_kernel<<<dim3(kCout / fb::kOTile, kB), 256, 0, stream>>>(
            x, Wt, gamma, beta, rmean, rvar, out);
    }
}

// Round 10
// 236.397 us; speedup vs baseline: 1.1555x; 1.1555x over previous
//
#include <hip/hip_runtime.h>
#include <math.h>

typedef _Float16 f16;
typedef __attribute__((ext_vector_type(8)))  _Float16 f16v8;
typedef __attribute__((ext_vector_type(4)))  __fp16   h16v4;
typedef __attribute__((ext_vector_type(16))) float    f32x16;
typedef __attribute__((ext_vector_type(4)))  float    f32x4;

namespace {
constexpr int kB = 64, kCin = 512, kT = 1024, kCout = 256;
constexpr size_t kYBytes     = (size_t)kB * kT * kCout * 4;    // 64 MiB y buffer ([b][o][t])
constexpr size_t kWfragBytes = (size_t)32 * 8 * 2 * 64 * 16;   // 512 KiB [kc][osub][plane][lane][16B]
constexpr size_t kSBytes     = kCout * 4;
constexpr size_t kWsNeed     = kYBytes + kWfragBytes + kSBytes;
}

// ---- prep: W' = 32*W split into 2 f16 planes (low plane scaled 2^11), A-frag order ----
// A-frag (32x32x16): m(o) = lane&31, k = (lane>>5)*8 + j.  Block (0,0,0) also fills sarr.
__global__ void wsplit16_kernel(const float* __restrict__ W, const float* __restrict__ gamma,
                                const float* __restrict__ rvar,
                                f16* __restrict__ wfrag, float* __restrict__ sarr) {
    const int kc = blockIdx.x, osub = blockIdx.y, p = blockIdx.z;
    const int lane = threadIdx.x;
    const int o  = osub * 32 + (lane & 31);
    const int kb = kc * 16 + (lane >> 5) * 8;
    f16v8 frag;
#pragma unroll
    for (int j = 0; j < 8; ++j) {
        const float w = 32.0f * W[o * kCin + kb + j];   // 2^5 pre-scale (denorm guard)
        const f16 h = (f16)w;                           // RNE
        const float r = w - (float)h;                   // exact
        const f16 l = (f16)(r * 2048.0f);               // low plane scaled 2^11
        frag[j] = p ? l : h;
    }
    *reinterpret_cast<f16v8*>(wfrag + ((size_t)((kc * 8 + osub) * 2 + p) * 64 + lane) * 8) = frag;
    if (kc == 0 && osub == 0 && p == 0) {
#pragma unroll
        for (int j = 0; j < 4; ++j) {
            const int oo = j * 64 + lane;
            sarr[oo] = (float)((double)gamma[oo] / sqrt((double)rvar[oo] + 1e-5));
        }
    }
}

// ---- GEMM: R8 engine (best verified: 86.5us, BT=128) + same-XCD x-sharing grid ----
// R9 accounting: fixed overhead+wsplit = 139.6us, lif = 18us, gemm wall = 86.5us.
// Kernel body is byte-identical to R8. Only the grid decode changes: linear id L
// with L%8 = b%8 puts ALL 8 t-chunk blocks of batch b on the SAME XCD (default
// round-robin), so x[b] (2MB) is fetched into that XCD's 4MB L2 once and shared,
// instead of being served 8x from L3. W (512KB) is L2-resident per XCD anyway.
// Block: 512 thr = 8 waves, tile 256o x 128t; wave w = osub w (32o) x 128t
// (4 tsub): acc = 8 x f32x16 = 128 AGPR. LDS Bd = 4 bufs x 128t x 20dw = 40 KiB.
__global__ __launch_bounds__(512, 2)
void gemm_f16_kernel(const float* __restrict__ x, const f16* __restrict__ wfrag,
                     const float* __restrict__ sarr, const float* __restrict__ rmean,
                     const float* __restrict__ beta, float* __restrict__ yt) {
    __shared__ unsigned int Bd[4][128 * 20];   // [buf][t*20 + 4*slot' + dword], 40 KiB

    const int tid  = threadIdx.x;
    const int lane = tid & 63;
    const int wave = tid >> 6;          // 0..7: osub (compute)
    const int n = lane & 31, q = lane >> 5;

    // same-XCD decode: L%8 = b%8; all 8 t-chunks of b share one XCD's L2
    const int bid  = blockIdx.x;
    const int rest = bid >> 3;
    const int b    = (bid & 7) + 8 * (rest >> 3);
    const int tg0  = (rest & 7) * 128;
    const int osg  = wave;                                  // global osub 0..7
    const float* __restrict__ xb = x + ((size_t)b << 19);   // b*512*1024
    const f16v8* __restrict__ wf = reinterpret_cast<const f16v8*>(wfrag);

    const int st_t = tid & 127;         // t index this thread stages (0..127)
    const int kpp  = tid >> 7;          // k-quad index 0..3 (k = 4*kpp..4*kpp+3)
    const int st_sw = (st_t >> 3) & 3;
    const int wr_base = 20 * st_t + 2 * (kpp & 1);
    const int s0 = ((0 + (kpp >> 1)) ^ st_sw) * 4;   // plane0 slot offset (dwords)
    const int s1 = ((2 + (kpp >> 1)) ^ st_sw) * 4;   // plane1 slot offset

    f32x16 accA[4] = {};   // [tsub] hh
    f32x16 accB[4] = {};   // [tsub] cross (scaled 2^11)
    f16v8  af[2][2];       // [buf][plane]
    float  xq[4][4];       // [slot][r] 4-deep x prefetch queue

    auto loadX = [&](int kc, float (&xd)[4]) {
        const float* px = xb + (size_t)(kc * 16 + 4 * kpp) * kT + tg0 + st_t;
#pragma unroll
        for (int r = 0; r < 4; ++r) xd[r] = px[(size_t)r * kT];
    };
    auto loadA = [&](int kc, f16v8 (&ad)[2]) {
#pragma unroll
        for (int pp = 0; pp < 2; ++pp)
            ad[pp] = wf[(size_t)((kc * 8 + osg) * 2 + pp) * 64 + lane];
    };
    auto stage = [&](int buf, const float (&xd)[4]) {
        auto h01 = __builtin_amdgcn_cvt_pkrtz(xd[0], xd[1]);   // RTZ pack
        auto h23 = __builtin_amdgcn_cvt_pkrtz(xd[2], xd[3]);
        auto l01 = __builtin_amdgcn_cvt_pkrtz((xd[0] - (float)h01[0]) * 2048.0f,
                                              (xd[1] - (float)h01[1]) * 2048.0f);
        auto l23 = __builtin_amdgcn_cvt_pkrtz((xd[2] - (float)h23[0]) * 2048.0f,
                                              (xd[3] - (float)h23[1]) * 2048.0f);
        h16v4 hv, lv;
        hv[0] = h01[0]; hv[1] = h01[1]; hv[2] = h23[0]; hv[3] = h23[1];
        lv[0] = l01[0]; lv[1] = l01[1]; lv[2] = l23[0]; lv[3] = l23[1];
        *reinterpret_cast<h16v4*>(&Bd[buf][wr_base + s0]) = hv;   // ds_write_b64
        *reinterpret_cast<h16v4*>(&Bd[buf][wr_base + s1]) = lv;
    };
    auto domfma = [&](int buf, const f16v8 (&ad)[2]) {
        __builtin_amdgcn_s_setprio(1);
#pragma unroll
        for (int s = 0; s < 4; ++s) {
            const int t = s * 32 + n;
            const int sw = (t >> 3) & 3;
            const f16v8 bh = *reinterpret_cast<const f16v8*>(&Bd[buf][20 * t + 4 * ((0 + q) ^ sw)]);
            const f16v8 bl = *reinterpret_cast<const f16v8*>(&Bd[buf][20 * t + 4 * ((2 + q) ^ sw)]);
            accA[s] = __builtin_amdgcn_mfma_f32_32x32x16_f16(ad[0], bh, accA[s], 0, 0, 0);
            accB[s] = __builtin_amdgcn_mfma_f32_32x32x16_f16(ad[0], bl, accB[s], 0, 0, 0);
            accB[s] = __builtin_amdgcn_mfma_f32_32x32x16_f16(ad[1], bh, accB[s], 0, 0, 0);
        }
        __builtin_amdgcn_s_setprio(0);
    };

    // prologue: fill 4-deep x queue, A buf 0, stage chunks 0 and 1
    loadX(0, xq[0]); loadX(1, xq[1]); loadX(2, xq[2]); loadX(3, xq[3]);
    loadA(0, af[0]);
    stage(0, xq[0]);
    stage(1, xq[1]);
    asm volatile("s_waitcnt lgkmcnt(0)\n\ts_barrier" ::: "memory");

    for (int kc4 = 0; kc4 < 8; ++kc4) {
#pragma unroll
        for (int u = 0; u < 4; ++u) {
            const int kc = kc4 * 4 + u;
            // all buffer/slot indices below are compile-time: kc&3==u, kc&1==u&1
            if (kc < 31) loadA(kc + 1, af[(u + 1) & 1]);
            if (kc < 30) stage((u + 2) & 3, xq[(u + 2) & 3]);   // stage chunk kc+2
            if (kc < 28) loadX(kc + 4, xq[u]);                  // refill slot
            domfma(u, af[u & 1]);
            if (u & 1)  // one barrier per 2 chunks; global loads stay in flight
                asm volatile("s_waitcnt lgkmcnt(0)\n\ts_barrier" ::: "memory");
        }
    }

    // ---- epilogue: combine planes, BN affine, store yt[b][o][t] (no LDS) ----
    // C/D: col(t)=lane&31, row(o)=(reg&3)+8*(reg>>2)+4*(lane>>5)
#pragma unroll
    for (int s = 0; s < 4; ++s) {
        const f32x16 v = accA[s] + accB[s] * 4.8828125e-4f;   // + cross/2^11
        const size_t t = (size_t)tg0 + s * 32 + n;
#pragma unroll
        for (int g = 0; g < 4; ++g) {
            const int og = osg * 32 + g * 8 + q * 4;
            const f32x4 sv = *reinterpret_cast<const f32x4*>(sarr + og);
            const f32x4 mv = *reinterpret_cast<const f32x4*>(rmean + og);
            const f32x4 bv = *reinterpret_cast<const f32x4*>(beta + og);
#pragma unroll
            for (int r2 = 0; r2 < 4; ++r2) {
                const int o = og + r2;
                // exact /32 un-scale, then BN (same per-element op order as before)
                const float val = (v[4 * g + r2] * 0.03125f - mv[r2]) * sv[r2] + bv[r2];
                yt[(((size_t)b << 8) + (size_t)o) * 1024 + t] = val;
            }
        }
    }
}

// ---- LIF: one wave per (b, 64-o slice); yt[b][o][t] rows are contiguous ----
// 1 wave/CU is fixed by the 16384 sequential chains, so BW = outstanding/latency:
// deepen the static prefetch queue 16->32 quads (32 KiB/wave in flight, ~8 MB
// chip-wide) to approach the ~6.3 TB/s ceiling. Same loads, same arithmetic
// order as the verified R8 lif -> bit-identical.
__global__ __launch_bounds__(64)
void lif_kernel(const float* __restrict__ yt, float* __restrict__ out) {
    const int b = blockIdx.x >> 2;
    const int o = ((blockIdx.x & 3) << 6) + threadIdx.x;
    const f32x4* __restrict__ row =
        reinterpret_cast<const f32x4*>(yt) + (((size_t)b << 8) + (size_t)o) * 256;
    float v = 0.f;
    int cnt = 0;
    f32x4 qb[32];
#pragma unroll
    for (int u = 0; u < 32; ++u) qb[u] = row[u];
    for (int g = 0; g < 7; ++g) {
#pragma unroll
        for (int u = 0; u < 32; ++u) {
            const f32x4 cv = qb[u];
            qb[u] = row[g * 32 + u + 32];   // distance-32 prefetch, static slot
#pragma unroll
            for (int e = 0; e < 4; ++e) {
                v = v + (cv[e] - v) * 0.5f;             // bit-exact reference recurrence
                if (v - 1.0f >= 0.0f) { ++cnt; v = 0.f; }
            }
        }
    }
#pragma unroll
    for (int u = 0; u < 32; ++u) {
        const f32x4 cv = qb[u];
#pragma unroll
        for (int e = 0; e < 4; ++e) {
            v = v + (cv[e] - v) * 0.5f;
            if (v - 1.0f >= 0.0f) { ++cnt; v = 0.f; }
        }
    }
    out[((size_t)b << 8) + o] = (float)cnt * (1.0f / 1024.0f);
}

// ---- fallback (round-1 fp32 fused path, unchanged) ----
namespace fb {
constexpr int kOTile = 32, kTTile = 128, kCc = 64;
constexpr int kNtt = kT / kTTile, kNcc = kCin / kCc, kYPad = 132;
}

__global__ void wt_transpose_kernel(const float* __restrict__ W, float* __restrict__ Wt) {
    int idx = blockIdx.x * 256 + threadIdx.x;
    int c = idx >> 8, o = idx & 255;
    Wt[idx] = W[o * kCin + c];
}

__global__ __launch_bounds__(256, 2)
void snn_fused_kernel(const float* __restrict__ x, const float* __restrict__ Wt,
                      const float* __restrict__ gamma, const float* __restrict__ beta,
                      const float* __restrict__ rmean, const float* __restrict__ rvar,
                      float* __restrict__ out) {
    using namespace fb;
    __shared__ float xs[kCc][kTTile];
    __shared__ float ws[kCc][kOTile];
    __shared__ float ytile[kOTile][kYPad];
    __shared__ float sarr[kOTile], barr[kOTile], marr[kOTile], vstate[kOTile];
    __shared__ int scnt[kOTile];
    const int tid = threadIdx.x, tx = tid & 31, ty = tid >> 5;
    const int b = blockIdx.y, o_blk = blockIdx.x * kOTile;
    if (tid < kOTile) {
        const int o = o_blk + tid;
        const double dinv = 1.0 / sqrt((double)rvar[o] + 1e-5);
        sarr[tid] = (float)(dinv * (double)gamma[o]);
        barr[tid] = beta[o]; marr[tid] = rmean[o];
        vstate[tid] = 0.0f; scnt[tid] = 0;
    }
    __syncthreads();
    const float* xb = x + (size_t)b * kCin * kT;
    for (int tt = 0; tt < kNtt; ++tt) {
        float acc[4][4];
#pragma unroll
        for (int i = 0; i < 4; ++i)
#pragma unroll
            for (int j = 0; j < 4; ++j) acc[i][j] = 0.0f;
        const int t0 = tt * kTTile;
        for (int cc = 0; cc < kNcc; ++cc) {
#pragma unroll
            for (int k = 0; k < 8; ++k) {
                const int f = tid + 256 * k;
                const int c = f >> 5, tq = f & 31;
                *reinterpret_cast<float4*>(&xs[c][tq * 4]) = *reinterpret_cast<const float4*>(
                    xb + (size_t)(cc * kCc + c) * kT + t0 + tq * 4);
            }
#pragma unroll
            for (int k = 0; k < 2; ++k) {
                const int f = tid + 256 * k;
                const int c = f >> 3, oq = f & 7;
                *reinterpret_cast<float4*>(&ws[c][oq * 4]) = *reinterpret_cast<const float4*>(
                    Wt + (size_t)(cc * kCc + c) * kCout + o_blk + oq * 4);
            }
            __syncthreads();
#pragma unroll 8
            for (int c = 0; c < kCc; ++c) {
                const float4 xv = *reinterpret_cast<const float4*>(&xs[c][tx * 4]);
                const float4 wv = *reinterpret_cast<const float4*>(&ws[c][ty * 4]);
                const float xf[4] = {xv.x, xv.y, xv.z, xv.w};
                const float wf4[4] = {wv.x, wv.y, wv.z, wv.w};
#pragma unroll
                for (int i = 0; i < 4; ++i)
#pragma unroll
                    for (int j = 0; j < 4; ++j) acc[i][j] += wf4[i] * xf[j];
            }
            __syncthreads();
        }
#pragma unroll
        for (int i = 0; i < 4; ++i) {
            const int o = ty * 4 + i;
            const float s = sarr[o], bb2 = barr[o], m = marr[o];
#pragma unroll
            for (int j = 0; j < 4; ++j) ytile[o][tx * 4 + j] = (acc[i][j] - m) * s + bb2;
        }
        __syncthreads();
        if (tid < kOTile) {
            float vv = vstate[tid];
            int cnt = 0;
#pragma unroll 4
            for (int t = 0; t < kTTile; ++t) {
                const float yv = ytile[tid][t];
                vv = vv + (yv - vv) * 0.5f;
                if (vv - 1.0f >= 0.0f) { cnt++; vv = 0.0f; }
            }
            vstate[tid] = vv; scnt[tid] += cnt;
        }
        __syncthreads();
    }
    if (tid < kOTile) out[b * kCout + o_blk + tid] = (float)scnt[tid] * (1.0f / 1024.0f);
}

extern "C" void kernel_launch(void* const* d_in, const int* in_sizes, int n_in,
                              void* d_out, int out_size, void* d_ws, size_t ws_size,
                              hipStream_t stream) {
    const float* x     = (const float*)d_in[0];
    const float* W     = (const float*)d_in[1];
    const float* gamma = (const float*)d_in[2];
    const float* beta  = (const float*)d_in[3];
    const float* rmean = (const float*)d_in[4];
    const float* rvar  = (const float*)d_in[5];
    float* out = (float*)d_out;

    if (ws_size >= kWsNeed) {
        float* yt    = (float*)d_ws;
        f16*   wfrag = (f16*)((char*)d_ws + kYBytes);
        float* sarr  = (float*)((char*)d_ws + kYBytes + kWfragBytes);
        wsplit16_kernel<<<dim3(32, 8, 2), 64, 0, stream>>>(W, gamma, rvar, wfrag, sarr);
        gemm_f16_kernel<<<dim3(512), 512, 0, stream>>>(x, wfrag, sarr, rmean, beta, yt);
        lif_kernel<<<256, 64, 0, stream>>>(yt, out);
    } else {
        float* Wt = (float*)d_ws;
        wt_transpose_kernel<<<(kCin * kCout) / 256, 256, 0, stream>>>(W, Wt);
        snn_fused_kernel<<<dim3(kCout / fb::kOTile, kB), 256, 0, stream>>>(
            x, Wt, gamma, beta, rmean, rvar, out);
    }
}